// Round 4
// baseline (18055.745 us; speedup 1.0000x reference)
//
#include <hip/hip_runtime.h>
#include <math.h>

#define VV 32000
#define BB 32
#define TT 128
#define HH 512
#define G4 2048   // 4*HH
#define BTT 4096  // BB*TT

#define L1_WGS 128
#define L2_WGS 256
#define NWG (L1_WGS + L2_WGS)

typedef unsigned short u16;
typedef __attribute__((ext_vector_type(8))) short short8;
typedef __attribute__((ext_vector_type(4))) float f32x4;

static __device__ __forceinline__ float sigm(float x) { return 1.0f / (1.0f + expf(-x)); }

// RNE split: v = hi + lo + eps, |eps| <= 2^-16 |v|
static __device__ __forceinline__ void bsplit(float v, u16& h, u16& l) {
    unsigned u = __float_as_uint(v);
    h = (u16)((u + 0x7FFFu + ((u >> 16) & 1u)) >> 16);
    float vh = __uint_as_float(((unsigned)h) << 16);
    unsigned u2 = __float_as_uint(v - vh);
    l = (u16)((u2 + 0x7FFFu + ((u2 >> 16) & 1u)) >> 16);
}

static __device__ __forceinline__ void gl_lds16(const void* g, void* l) {
    __builtin_amdgcn_global_load_lds(
        (const __attribute__((address_space(1))) void*)g,
        (__attribute__((address_space(3))) void*)l, 16, 0, 0);
}

static __device__ __forceinline__ unsigned aload(const unsigned* p) {
    return __hip_atomic_load(p, __ATOMIC_RELAXED, __HIP_MEMORY_SCOPE_AGENT);
}

// ---------- embedding gather + split ----------
__global__ void k_gather_split(const int* __restrict__ idx, const float* __restrict__ emb,
                               u16* __restrict__ hi, u16* __restrict__ lo) {
    int row = blockIdx.x;
    int e = idx[row];
    float4 v = ((const float4*)(emb + (size_t)e * HH))[threadIdx.x];
    ushort4 h4, l4;
    bsplit(v.x, h4.x, l4.x); bsplit(v.y, h4.y, l4.y);
    bsplit(v.z, h4.z, l4.z); bsplit(v.w, h4.w, l4.w);
    size_t o = (size_t)row * HH + threadIdx.x * 4;
    *(ushort4*)(hi + o) = h4;
    *(ushort4*)(lo + o) = l4;
}

__global__ void k_zero(unsigned* __restrict__ p, int n) {
    int i = blockIdx.x * blockDim.x + threadIdx.x;
    if (i < n) p[i] = 0u;
}

// ---------- fp32 transpose: dst[gc][k] = src[k][gc], k<K, gc<G4 ----------
__global__ void k_transposeN(const float* __restrict__ src, float* __restrict__ dst, int K) {
    int gc = blockIdx.x;
    float* d = dst + (size_t)gc * K;
    for (int k = threadIdx.x; k < K; k += blockDim.x)
        d[k] = src[(size_t)k * G4 + gc];
}

// ---------- transpose + split: src fp32 [K][N] -> dhi/dlo bf16 [N][K] ----------
__global__ __launch_bounds__(256) void k_tsplit(const float* __restrict__ src,
                                                u16* __restrict__ dhi, u16* __restrict__ dlo,
                                                int K, int N) {
    __shared__ float t[32][33];
    int kb = blockIdx.y << 5, nb = blockIdx.x << 5;
    int r = threadIdx.x >> 5, c = threadIdx.x & 31;
    #pragma unroll
    for (int it = 0; it < 4; ++it)
        t[it * 8 + r][c] = src[(size_t)(kb + it * 8 + r) * N + nb + c];
    __syncthreads();
    #pragma unroll
    for (int it = 0; it < 4; ++it) {
        int n = nb + it * 8 + r, k = kb + c;
        u16 h, l;
        bsplit(t[c][it * 8 + r], h, l);
        dhi[(size_t)n * K + k] = h;
        dlo[(size_t)n * K + k] = l;
    }
}

// ---------- bf16x3 split MFMA GEMM (unchanged, verified passing) ----------
__global__ __launch_bounds__(256) void k_mgemm(const u16* __restrict__ Ah, const u16* __restrict__ Al,
                                               const u16* __restrict__ Bh, const u16* __restrict__ Bl,
                                               const float* __restrict__ bias, float* __restrict__ C,
                                               int N, int K) {
    __shared__ u16 lds[4][4096];
    const int tid = threadIdx.x;
    const int lane = tid & 63, wid = tid >> 6;
    const int wm = wid >> 1, wn = wid & 1;
    const int lm = lane & 15, kg = lane >> 4;
    const size_t mbase = (size_t)blockIdx.y * 128, nbase = (size_t)blockIdx.x * 128;

    f32x4 acc[4][4] = {};

    const int q = wid * 128 + lane;
    for (int k0 = 0; k0 < K; k0 += 32) {
        __syncthreads();
        #pragma unroll
        for (int i = 0; i < 2; ++i) {
            int qq = q + i * 64;
            int kgs = qq >> 7, ms = qq & 127;
            size_t ga = (mbase + ms) * K + k0 + kgs * 8;
            size_t gb = (nbase + ms) * K + k0 + kgs * 8;
            int lb_ = (wid * 2 + i) * 512;
            gl_lds16(Ah + ga, &lds[0][lb_]);
            gl_lds16(Al + ga, &lds[1][lb_]);
            gl_lds16(Bh + gb, &lds[2][lb_]);
            gl_lds16(Bl + gb, &lds[3][lb_]);
        }
        __syncthreads();

        short8 ah[4], al[4], bh[4], bl[4];
        const int abase = (kg * 128 + wm * 64 + lm) * 8;
        const int bbase = (kg * 128 + wn * 64 + lm) * 8;
        #pragma unroll
        for (int f = 0; f < 4; ++f) {
            ah[f] = *(const short8*)&lds[0][abase + f * 128];
            al[f] = *(const short8*)&lds[1][abase + f * 128];
            bh[f] = *(const short8*)&lds[2][bbase + f * 128];
            bl[f] = *(const short8*)&lds[3][bbase + f * 128];
        }
        #pragma unroll
        for (int fm = 0; fm < 4; ++fm)
            #pragma unroll
            for (int fn = 0; fn < 4; ++fn) {
                acc[fm][fn] = __builtin_amdgcn_mfma_f32_16x16x32_bf16(ah[fm], bh[fn], acc[fm][fn], 0, 0, 0);
                acc[fm][fn] = __builtin_amdgcn_mfma_f32_16x16x32_bf16(ah[fm], bl[fn], acc[fm][fn], 0, 0, 0);
                acc[fm][fn] = __builtin_amdgcn_mfma_f32_16x16x32_bf16(al[fm], bh[fn], acc[fm][fn], 0, 0, 0);
            }
    }

    float bv[4];
    #pragma unroll
    for (int fn = 0; fn < 4; ++fn) bv[fn] = bias[nbase + wn * 64 + fn * 16 + lm];
    #pragma unroll
    for (int fm = 0; fm < 4; ++fm) {
        size_t row0 = mbase + wm * 64 + fm * 16 + kg * 4;
        #pragma unroll
        for (int fn = 0; fn < 4; ++fn) {
            size_t col = nbase + wn * 64 + fn * 16 + lm;
            #pragma unroll
            for (int r = 0; r < 4; ++r)
                C[(row0 + r) * N + col] = acc[fm][fn][r] + bv[fn];
        }
    }
}

// ---------- persistent 2-layer LSTM: ONE launch, device-scope layer barriers ----------
// Grid 384 x 256, __launch_bounds__(256,2): 384 <= 2 blocks/CU * 256 CU -> all resident.
// WGs [0,128):  layer 1. WG owns 4 chans x 32 batches. Lane layout tid=(cl<<6)|(half<<5)|b:
//   32-lane group shares 2 weight rows (broadcast); half0 computes i,j; half1 f,o.
// WGs [128,384): layer 2. WG owns 2 chans x 32 batches. tid=(cl<<7)|(g<<5)|b: one
//   dot-1024 per thread over [h1out[s](512); h2[s-1](512)].
// hall1/hall2: [TT][BB][HH] write-once history; c-state in registers.
// Barriers: monotonic counters, release (__threadfence) before arrival, acquire after spin.
// L1 never waits on L2 -> L1 free-runs; L2 trails on cnt1. Spins bounded (no-hang safety).
__global__ __launch_bounds__(256, 2) void k_lstm(const float* __restrict__ wt1,   // [2048][512]
                                                 const float* __restrict__ wt2,   // [2048][1024]
                                                 const float* __restrict__ xg1,   // [BTT][2048] incl b1
                                                 const float* __restrict__ lb2,   // [2048]
                                                 float* __restrict__ hall1,       // [TT][BB][HH]
                                                 float* __restrict__ hall2,       // [TT][BB][HH]
                                                 unsigned* __restrict__ sync) {   // [>=2], zeroed
    __shared__ float gs[4][4][32];
    const int tid = threadIdx.x;
    const int b = tid & 31;

    if (blockIdx.x < L1_WGS) {
        // ================= layer 1 =================
        const int cl = tid >> 6, half = (tid >> 5) & 1;
        const int chan = blockIdx.x * 4 + cl;
        const float4* w0 = (const float4*)(wt1 + (size_t)((half * 2 + 0) * HH + chan) * HH);
        const float4* w1 = (const float4*)(wt1 + (size_t)((half * 2 + 1) * HH + chan) * HH);
        float c_reg = 0.f;
        for (int s = 0; s < TT; ++s) {
            size_t xrow = ((size_t)b * TT + s) * G4;
            float a0 = xg1[xrow + (half * 2 + 0) * HH + chan];
            float a1 = xg1[xrow + (half * 2 + 1) * HH + chan];
            if (s > 0) {
                const float4* inp = (const float4*)(hall1 + ((size_t)(s - 1) * BB + b) * HH);
                #pragma unroll 4
                for (int k = 0; k < HH / 4; ++k) {
                    float4 x4 = inp[k], p4 = w0[k], q4 = w1[k];
                    a0 += p4.x * x4.x + p4.y * x4.y + p4.z * x4.z + p4.w * x4.w;
                    a1 += q4.x * x4.x + q4.y * x4.y + q4.z * x4.z + q4.w * x4.w;
                }
            }
            if (half == 0) gs[cl][0][b] = sigm(a0) * tanhf(a1);   // sig(i)*tanh(j)
            else         { gs[cl][2][b] = sigm(a0); gs[cl][3][b] = sigm(a1); }  // sig(f), sig(o)
            __syncthreads();
            if (half == 0) {
                float nc = c_reg * gs[cl][2][b] + gs[cl][0][b];
                float nh = tanhf(nc) * gs[cl][3][b];
                c_reg = nc;
                hall1[((size_t)s * BB + b) * HH + chan] = nh;
            }
            __threadfence();        // release hall1[s]
            __syncthreads();
            if (tid == 0) {
                __hip_atomic_fetch_add(&sync[0], 1u, __ATOMIC_RELAXED, __HIP_MEMORY_SCOPE_AGENT);
                unsigned it = 0, tgt = (unsigned)(L1_WGS * (s + 1));
                while (aload(&sync[0]) < tgt && ++it < (1u << 22)) __builtin_amdgcn_s_sleep(2);
            }
            __syncthreads();
            __threadfence();        // acquire peers' hall1[s]
        }
    } else {
        // ================= layer 2 =================
        const int idx = blockIdx.x - L1_WGS;
        const int cl = tid >> 7, g = (tid >> 5) & 3;
        const int chan = idx * 2 + cl;
        const int gcol = g * HH + chan;
        const float4* wx = (const float4*)(wt2 + (size_t)gcol * 1024);
        const float4* wh = wx + HH / 4;
        const float bias = lb2[gcol];
        float c_reg = 0.f;
        for (int s = 0; s < TT; ++s) {
            if (tid == 0) {          // wait for hall1[s]
                unsigned it = 0, tgt = (unsigned)(L1_WGS * (s + 1));
                while (aload(&sync[0]) < tgt && ++it < (1u << 22)) __builtin_amdgcn_s_sleep(2);
            }
            __syncthreads();
            __threadfence();        // acquire hall1[s]
            float a = bias;
            {
                const float4* xin = (const float4*)(hall1 + ((size_t)s * BB + b) * HH);
                #pragma unroll 4
                for (int k = 0; k < HH / 4; ++k) {
                    float4 x4 = xin[k], p4 = wx[k];
                    a += p4.x * x4.x + p4.y * x4.y + p4.z * x4.z + p4.w * x4.w;
                }
            }
            if (s > 0) {
                const float4* hin = (const float4*)(hall2 + ((size_t)(s - 1) * BB + b) * HH);
                #pragma unroll 4
                for (int k = 0; k < HH / 4; ++k) {
                    float4 x4 = hin[k], p4 = wh[k];
                    a += p4.x * x4.x + p4.y * x4.y + p4.z * x4.z + p4.w * x4.w;
                }
            }
            gs[cl][g][b] = (g == 1) ? tanhf(a) : sigm(a);
            __syncthreads();
            if (g == 0) {
                float nc = c_reg * gs[cl][2][b] + gs[cl][0][b] * gs[cl][1][b];
                float nh = tanhf(nc) * gs[cl][3][b];
                c_reg = nc;
                hall2[((size_t)s * BB + b) * HH + chan] = nh;
            }
            __threadfence();        // release hall2[s]
            __syncthreads();
            if (tid == 0) {
                __hip_atomic_fetch_add(&sync[1], 1u, __ATOMIC_RELAXED, __HIP_MEMORY_SCOPE_AGENT);
                unsigned it = 0, tgt = (unsigned)(L2_WGS * (s + 1));
                while (aload(&sync[1]) < tgt && ++it < (1u << 22)) __builtin_amdgcn_s_sleep(2);
            }
            __syncthreads();
            __threadfence();        // acquire peers' hall2[s]
        }
    }
}

// ---------- hall2 [TT][BB][HH] -> xa rows (b*TT+t) + bf16 split ----------
__global__ void k_splitTB(const float* __restrict__ hall2, u16* __restrict__ hi,
                          u16* __restrict__ lo) {
    int r = blockIdx.x;              // output row = b*TT + t
    int bb = r >> 7, t = r & (TT - 1);
    float4 v = ((const float4*)(hall2 + ((size_t)t * BB + bb) * HH))[threadIdx.x];
    ushort4 h4, l4;
    bsplit(v.x, h4.x, l4.x); bsplit(v.y, h4.y, l4.y);
    bsplit(v.z, h4.z, l4.z); bsplit(v.w, h4.w, l4.w);
    size_t o = (size_t)r * HH + threadIdx.x * 4;
    *(ushort4*)(hi + o) = h4;
    *(ushort4*)(lo + o) = l4;
}

// ---------- per-row CE loss: online logsumexp over V ----------
__global__ __launch_bounds__(256) void k_loss(const float* __restrict__ logits,
                                              const int* __restrict__ tgt,
                                              float* __restrict__ rowloss) {
    int row = blockIdx.x;
    const float* lr = logits + (size_t)row * VV;
    float m = -INFINITY, s = 0.f;
    for (int c = threadIdx.x; c < VV; c += 256) {
        float x = lr[c];
        if (x > m) { s = s * __expf(m - x) + 1.f; m = x; }
        else       { s += __expf(x - m); }
    }
    #pragma unroll
    for (int off = 32; off > 0; off >>= 1) {
        float mo = __shfl_down(m, off);
        float so = __shfl_down(s, off);
        if (mo > m) { s = s * __expf(m - mo) + so; m = mo; }
        else        { s += so * __expf(mo - m); }
    }
    __shared__ float sm[4], ss[4];
    int wid = threadIdx.x >> 6;
    if ((threadIdx.x & 63) == 0) { sm[wid] = m; ss[wid] = s; }
    __syncthreads();
    if (threadIdx.x == 0) {
        m = sm[0]; s = ss[0];
        for (int w = 1; w < 4; ++w) {
            float mo = sm[w], so = ss[w];
            if (mo > m) { s = s * __expf(m - mo) + so; m = mo; }
            else        { s += so * __expf(mo - m); }
        }
        float tl = lr[tgt[row]];
        rowloss[row] = -(tl - m - logf(s));
    }
}

__global__ void k_meanloss(const float* __restrict__ rowloss, float* __restrict__ out) {
    float s = 0.f;
    for (int i = threadIdx.x; i < BTT; i += 256) s += rowloss[i];
    #pragma unroll
    for (int off = 32; off > 0; off >>= 1) s += __shfl_down(s, off);
    __shared__ float wsum[4];
    int wid = threadIdx.x >> 6;
    if ((threadIdx.x & 63) == 0) wsum[wid] = s;
    __syncthreads();
    if (threadIdx.x == 0) out[0] = (wsum[0] + wsum[1] + wsum[2] + wsum[3]) * (1.0f / BTT);
}

extern "C" void kernel_launch(void* const* d_in, const int* in_sizes, int n_in,
                              void* d_out, int out_size, void* d_ws, size_t ws_size,
                              hipStream_t stream) {
    const int*   ids = (const int*)d_in[0];
    const int*   tgt = (const int*)d_in[1];
    const float* emb = (const float*)d_in[2];
    const float* lw  = (const float*)d_in[3];
    const float* lb  = (const float*)d_in[4];
    const float* sw  = (const float*)d_in[5];
    const float* sb  = (const float*)d_in[6];
    float* logits = (float*)d_out;
    float* cost   = logits + (size_t)BTT * VV;

    // ---- ws layout ----
    float* hall1 = (float*)d_ws;            // [TT][BB][HH] (8MB)
    float* hall2 = hall1 + 2097152;         // (8MB)
    float* xgbuf = hall2 + 2097152;         // [BTT][2048] (32MB)
    float* wt1   = xgbuf + 8388608;         // [2048][512] (4MB)
    float* wt2   = wt1 + 1048576;           // [2048][1024] (8MB)
    float* rloss = wt2 + 2097152;           // 4096
    unsigned* syncv = (unsigned*)(rloss + 4096);  // 16 words
    u16* xa_hi  = (u16*)(syncv + 16);       // [BTT][HH] (4MB)
    u16* xa_lo  = xa_hi + (size_t)BTT * HH;
    u16* wxt_hi = xa_lo + (size_t)BTT * HH; // L1 Wx^T [2048][512] (2MB)
    u16* wxt_lo = wxt_hi + (size_t)G4 * HH;
    u16* swt_hi = wxt_lo + (size_t)G4 * HH; // [32000][512] (32.8MB)
    u16* swt_lo = swt_hi + (size_t)VV * HH;

    // ---- preprocessing ----
    k_transposeN<<<G4, 128, 0, stream>>>(lw + (size_t)HH * G4, wt1, HH);         // L1 h-half
    k_transposeN<<<G4, 128, 0, stream>>>(lw + (size_t)2 * HH * G4, wt2, 2 * HH); // L2 full
    {
        dim3 gt(G4 / 32, HH / 32);
        k_tsplit<<<gt, 256, 0, stream>>>(lw, wxt_hi, wxt_lo, HH, G4);            // L1 x-half
    }
    {
        dim3 gt(VV / 32, HH / 32);
        k_tsplit<<<gt, 256, 0, stream>>>(sw, swt_hi, swt_lo, HH, VV);
    }
    k_gather_split<<<BTT, 128, 0, stream>>>(ids, emb, xa_hi, xa_lo);
    k_zero<<<1, 64, 0, stream>>>(syncv, 16);

    // ---- layer-1 input gates: xg = x_emb @ W1x + b1 ----
    dim3 gg(G4 / 128, BTT / 128);
    k_mgemm<<<gg, 256, 0, stream>>>(xa_hi, xa_lo, wxt_hi, wxt_lo, lb, xgbuf, G4, HH);

    // ---- persistent recurrence: ONE launch ----
    k_lstm<<<NWG, 256, 0, stream>>>(wt1, wt2, xgbuf, lb + G4, hall1, hall2, syncv);

    // ---- projection ----
    k_splitTB<<<BTT, 128, 0, stream>>>(hall2, xa_hi, xa_lo);
    dim3 gp(VV / 128, BTT / 128);
    k_mgemm<<<gp, 256, 0, stream>>>(xa_hi, xa_lo, swt_hi, swt_lo, sb, logits, VV, HH);
    k_loss<<<BTT, 256, 0, stream>>>(logits, tgt, rloss);
    k_meanloss<<<1, 256, 0, stream>>>(rloss, cost);
}